// Round 8
// baseline (104.530 us; speedup 1.0000x reference)
//
#include <hip/hip_runtime.h>
#include <hip/hip_bf16.h>
#include <stdint.h>
#include <stddef.h>

// Problem constants
#define NIMG 32
#define C_IN 128
#define C_OUT 256
#define HW 56
#define SP 3136            // 56*56
#define STOT (NIMG * SP)   // 100352
#define PD 58              // padded spatial dim
#define KTOT 1152

// Tiling: BM=128 (2 M-tiles), BN=224 = 4 image rows -> B window 6x58x128 in LDS
#define BM 128
#define BN 224
#define NTILE 896          // 2 * 448
#define THREADS 512
#define WIN_SH 44544       // 6*58*128 shorts (89088 B)
#define ABUF_SH 4096       // 128 rows x 32 ci shorts (8 KB)
#define LDS_BYTES (2 * (WIN_SH + 8 * ABUF_SH))   // 154624

typedef __attribute__((ext_vector_type(8))) short bf16x8;
typedef __attribute__((ext_vector_type(4))) float f32x4;

__device__ __forceinline__ void gload16(const void* g, void* l) {
    __builtin_amdgcn_global_load_lds(
        (const __attribute__((address_space(1))) void*)g,
        (__attribute__((address_space(3))) void*)l,
        16, 0, 0);
}

#define BAR() do { asm volatile("" ::: "memory"); \
                   __builtin_amdgcn_s_barrier();  \
                   asm volatile("" ::: "memory"); } while (0)
#define VMCNT(n) asm volatile("s_waitcnt vmcnt(" #n ")" ::: "memory")
#define LGKM0() asm volatile("s_waitcnt lgkmcnt(0)" ::: "memory")

__device__ __forceinline__ unsigned short bf2u(float f) {
    __hip_bfloat16 b = __float2bfloat16(f);
    return *reinterpret_cast<unsigned short*>(&b);
}

// ---------------------------------------------------------------------------
// Prepass (merged): pad+transpose x -> padded NHWC bf16 [n][58][58][128]
// (borders zeroed inline) + weights OIHW fp32 -> [tap][co][ci] bf16.
// ---------------------------------------------------------------------------
#define PAD_BLOCKS (NIMG * PD)                 // 1856
#define WT_BLOCKS  ((9 * C_OUT * C_IN) / 256)  // 1152

__global__ __launch_bounds__(256)
void prep_kernel(const float* __restrict__ x, const float* __restrict__ wgt,
                 __hip_bfloat16* __restrict__ xp, __hip_bfloat16* __restrict__ wt) {
    __shared__ float t[C_IN][HW + 1];
    const int b = blockIdx.x;
    if (b < PAD_BLOCKS) {
        const int hp = b % PD;
        const int n  = b / PD;
        const int h  = hp - 1;
        const bool interior = ((unsigned)h < (unsigned)HW);
        if (interior) {
            for (int idx = threadIdx.x; idx < C_IN * HW; idx += 256) {
                int ci = idx / HW, w = idx - ci * HW;
                t[ci][w] = x[((size_t)n * C_IN + ci) * SP + h * HW + w];
            }
        }
        __syncthreads();
        ushort4* dst = (ushort4*)(xp + ((size_t)n * PD + hp) * PD * C_IN);
        for (int idx = threadIdx.x; idx < PD * C_IN / 4; idx += 256) {
            int el = idx * 4;
            int wp = el >> 7, c0 = el & 127;
            ushort4 v = {0, 0, 0, 0};
            if (interior && wp >= 1 && wp <= HW) {
                int w = wp - 1;
                v.x = bf2u(t[c0 + 0][w]);
                v.y = bf2u(t[c0 + 1][w]);
                v.z = bf2u(t[c0 + 2][w]);
                v.w = bf2u(t[c0 + 3][w]);
            }
            dst[idx] = v;
        }
    } else {
        int idx = (b - PAD_BLOCKS) * 256 + threadIdx.x;   // 294912 exact
        int ci  = idx & 127;
        int co  = (idx >> 7) & 255;
        int tap = idx >> 15;
        wt[idx] = __float2bfloat16(wgt[(co * C_IN + ci) * 9 + tap]);
    }
}

// ---------------------------------------------------------------------------
// Main: implicit GEMM, 128x224 tile, 8 waves (4M x 2N, wave tile 32x112).
// B: entire padded 6x58x128 window (89 KB) loaded to LDS ONCE per tile;
//    the 9 taps are read-offset shifts; chunk-XOR swizzle cq^=(w'&7)
//    (inverse-swizzled gload source + swizzled ds_read).
// A: ring-8 of 8KB slices (64 KB), staged distance-3 half-taps ahead,
//    1 gload/thread/slice.  18 half-taps; per half-tap:
//      VMCNT(4|2|0); LGKM0-before-BAR; BAR; stage 2 slices; read 4 A-frags +
//      14 B-frags; 28 MFMA  (no inner barriers -> compiler pipelines).
// VMCNT induction: at half-tap h, outstanding = slices 2h..2h+5 (6);
// VMCNT(4) retires 2h,2h+1 (the two being read). h=16 -> 2, h=17 -> 0.
// ---------------------------------------------------------------------------
__global__ __launch_bounds__(THREADS, 2)
void conv_mfma_kernel(const __hip_bfloat16* __restrict__ xp,
                      const __hip_bfloat16* __restrict__ wt,
                      const float* __restrict__ bias,
                      float* __restrict__ out) {
    extern __shared__ short smem[];          // window | 8 A-bufs
    short* smemA = smem + WIN_SH;

    const int tid  = threadIdx.x;
    const int lane = tid & 63;
    const int wid  = tid >> 6;
    const int rl   = lane & 15;
    const int kq   = lane >> 4;

    // tile mapping: XCD-chunked, window pairs adjacent
    const int gt  = (blockIdx.x & 7) * 112 + (blockIdx.x >> 3);  // 896 = 8*112
    const int m0  = gt & 1;                  // M-tile (co 0..127 / 128..255)
    const int nt  = gt >> 1;                 // 0..447 spatial tile
    const int img = nt / 14;
    const int R0  = (nt - img * 14) * 4;     // first output row of tile
    const int s0  = nt * BN;

    // ---- A staging constants (inverse-swizzled source, proven scheme) ----
    const int cg_el = (((lane & 3) ^ ((lane >> 3) & 3)) << 3);
    const int srow  = wid * 16 + (lane >> 2);          // 0..127
    // ---- A read offsets ----
    const int rch = ((kq ^ ((lane >> 1) & 3)) << 3);
    const int wmA = (wid >> 1) * 32;         // 4 M-waves: 32 rows each
    const int wn  = (wid & 1) * 112;         // 2 N-waves
    const int aRd = (wmA + rl) * 32 + rch;

    // ---- per-ni window read bases ----
    int wrb[7], wc0[7];
    #pragma unroll
    for (int ni = 0; ni < 7; ++ni) {
        int soff = wn + ni * 16 + rl;        // 0..223
        int lr   = soff / 56;
        int wc   = soff - lr * 56;
        wrb[ni]  = lr * 58 + wc;
        wc0[ni]  = wc;
    }

    auto STG_A = [&](int s) {   // stage A slice s (8 KB) into buf s&7
        const __hip_bfloat16* src = wt + ((s >> 2) << 15)
            + (((m0 << 7) + srow) << 7) + ((s & 3) << 5) + cg_el;
        gload16(src, smemA + (s & 7) * ABUF_SH + wid * 512);
    };

    // ---- prologue: window load (87 wave-groups) + A slices 0..5 ----
    {
        const int xbase = ((img * PD) + R0) * PD * C_IN;   // element base
        for (int g = wid; g < 87; g += 8) {
            int e    = g * 512 + (lane << 3);
            int r    = e / 7424;             // 7424 = 58*128
            int rem  = e - r * 7424;
            int wcol = rem >> 7;
            int c    = (rem >> 3) & 15;
            int csw  = c ^ (wcol & 7);
            gload16(xp + xbase + e + ((csw - c) << 3), smem + g * 512);
        }
        #pragma unroll
        for (int s = 0; s < 6; ++s) STG_A(s);
    }

    // bias preload
    float bv[2][4];
    #pragma unroll
    for (int mi = 0; mi < 2; ++mi)
        #pragma unroll
        for (int j = 0; j < 4; ++j)
            bv[mi][j] = bias[(m0 << 7) + wmA + mi * 16 + (kq << 2) + j];

    f32x4 acc[2][7] = {};

    for (int h = 0; h < 18; ++h) {
        if (h < 16)       { VMCNT(4); }
        else if (h == 16) { VMCNT(2); }
        else              { VMCNT(0); }
        LGKM0();           // all prior ds_reads serviced before barrier
        BAR();
        if (h <= 14) { STG_A(2 * h + 6); STG_A(2 * h + 7); }

        const int tap    = h >> 1;
        const int kh     = (tap * 11) >> 5;
        const int kw     = tap - kh * 3;
        const int tapoff = kh * 58 + kw;
        const int kbase  = (h & 1) << 1;     // kk = kbase, kbase+1

        bf16x8 fa[2][2], fb[2][7];
        #pragma unroll
        for (int u = 0; u < 2; ++u) {
            const int s = (tap << 2) + kbase + u;
            const short* Ab = smemA + (s & 7) * ABUF_SH;
            #pragma unroll
            for (int mi = 0; mi < 2; ++mi)
                fa[u][mi] = *(const bf16x8*)(Ab + aRd + mi * 512);
            const int cqb = ((kbase + u) << 2) + kq;
            #pragma unroll
            for (int ni = 0; ni < 7; ++ni) {
                int eb = (wrb[ni] + tapoff) << 7;
                int sw = (wc0[ni] + kw) & 7;
                fb[u][ni] = *(const bf16x8*)(smem + eb + ((cqb ^ sw) << 3));
            }
        }
        __builtin_amdgcn_s_setprio(1);
        #pragma unroll
        for (int u = 0; u < 2; ++u)
            #pragma unroll
            for (int mi = 0; mi < 2; ++mi)
                #pragma unroll
                for (int ni = 0; ni < 7; ++ni)
                    acc[mi][ni] = __builtin_amdgcn_mfma_f32_16x16x32_bf16(
                        fa[u][mi], fb[u][ni], acc[mi][ni], 0, 0, 0);
        __builtin_amdgcn_s_setprio(0);
    }

    // ---- epilogue: D col = spatial (lane&15), row = co ----
    #pragma unroll
    for (int ni = 0; ni < 7; ++ni) {
        int s  = s0 + wn + ni * 16 + rl;
        int si = s - img * SP;
        float* obase = out + (size_t)img * C_OUT * SP + si;
        #pragma unroll
        for (int mi = 0; mi < 2; ++mi) {
            int cob = (m0 << 7) + wmA + mi * 16 + (kq << 2);
            #pragma unroll
            for (int j = 0; j < 4; ++j) {
                obase[(size_t)(cob + j) * SP] = acc[mi][ni][j] + bv[mi][j];
            }
        }
    }
}

// ---------------------------------------------------------------------------
// Fallback: direct fp32 conv (only if ws too small). Slow but correct.
// ---------------------------------------------------------------------------
__global__ void conv_direct_kernel(const float* __restrict__ x,
                                   const float* __restrict__ wgt,
                                   const float* __restrict__ bias,
                                   float* __restrict__ out) {
    long idx = (long)blockIdx.x * 256 + threadIdx.x;
    if (idx >= (long)NIMG * C_OUT * SP) return;
    int si = (int)(idx % SP);
    int co = (int)((idx / SP) % C_OUT);
    int n  = (int)(idx / ((long)SP * C_OUT));
    int h = si / HW, w = si - (si / HW) * HW;
    float acc = bias[co];
    for (int ci = 0; ci < C_IN; ++ci) {
        const float* xr = x + ((size_t)n * C_IN + ci) * SP;
        const float* wr = wgt + ((size_t)co * C_IN + ci) * 9;
        #pragma unroll
        for (int kh = 0; kh < 3; ++kh) {
            int ih = h + kh - 1;
            if (ih < 0 || ih >= HW) continue;
            #pragma unroll
            for (int kw = 0; kw < 3; ++kw) {
                int iw = w + kw - 1;
                if (iw < 0 || iw >= HW) continue;
                acc += xr[ih * HW + iw] * wr[kh * 3 + kw];
            }
        }
    }
    out[idx] = acc;
}

// ---------------------------------------------------------------------------
extern "C" void kernel_launch(void* const* d_in, const int* in_sizes, int n_in,
                              void* d_out, int out_size, void* d_ws, size_t ws_size,
                              hipStream_t stream) {
    const float* x    = (const float*)d_in[0];
    const float* wgt  = (const float*)d_in[1];
    const float* bias = (const float*)d_in[2];
    float* out = (float*)d_out;

    const size_t xp_bytes = (size_t)NIMG * PD * PD * C_IN * sizeof(__hip_bfloat16);
    const size_t wt_bytes = (size_t)9 * C_OUT * C_IN * sizeof(__hip_bfloat16);

    if (ws_size >= xp_bytes + wt_bytes) {
        __hip_bfloat16* xp  = (__hip_bfloat16*)d_ws;
        __hip_bfloat16* wtb = (__hip_bfloat16*)((char*)d_ws + xp_bytes);

        prep_kernel<<<PAD_BLOCKS + WT_BLOCKS, 256, 0, stream>>>(x, wgt, xp, wtb);

        hipFuncSetAttribute((const void*)conv_mfma_kernel,
                            hipFuncAttributeMaxDynamicSharedMemorySize, LDS_BYTES);
        conv_mfma_kernel<<<NTILE, THREADS, LDS_BYTES, stream>>>(xp, wtb, bias, out);
    } else {
        long total = (long)NIMG * C_OUT * SP;
        conv_direct_kernel<<<(int)((total + 255) / 256), 256, 0, stream>>>(
            x, wgt, bias, out);
    }
}

// Round 9
// 85.068 us; speedup vs baseline: 1.2288x; 1.2288x over previous
//
#include <hip/hip_runtime.h>
#include <hip/hip_bf16.h>
#include <stdint.h>
#include <stddef.h>

// Problem constants
#define NIMG 32
#define C_IN 128
#define C_OUT 256
#define HW 56
#define SP 3136            // 56*56
#define STOT (NIMG * SP)   // 100352
#define PD 58              // padded spatial dim
#define KTOT 1152          // 128*9

// GEMM tiling
#define BM 256
#define BN 224             // 448 tiles = 8*56 (XCD-exact)
#define NSLICE 36          // K-slices of 32
#define THREADS 512

typedef __attribute__((ext_vector_type(8))) short bf16x8;
typedef __attribute__((ext_vector_type(4))) float f32x4;

__device__ __forceinline__ void gload16(const void* g, void* l) {
    __builtin_amdgcn_global_load_lds(
        (const __attribute__((address_space(1))) void*)g,
        (__attribute__((address_space(3))) void*)l,
        16, 0, 0);
}

// Memory-clobber only: orders all memory ops (ds_read/gload_lds) across the
// wait, but leaves register-only MFMAs free for the scheduler (m141 lesson:
// sched_barrier(0) order-pinning costs ~40%).
#define BAR() do { asm volatile("" ::: "memory"); \
                   __builtin_amdgcn_s_barrier();  \
                   asm volatile("" ::: "memory"); } while (0)
#define VMCNT(n) asm volatile("s_waitcnt vmcnt(" #n ")" ::: "memory")

__device__ __forceinline__ unsigned short bf2u(float f) {
    __hip_bfloat16 b = __float2bfloat16(f);
    return *reinterpret_cast<unsigned short*>(&b);
}

// ---------------------------------------------------------------------------
// Prepass (merged): blocks [0, NIMG*PD) pad+transpose x -> padded NHWC bf16
// [n][58][58][128] with zeroed borders; blocks [NIMG*PD, +1152) transform
// weights OIHW fp32 -> [tap][co][ci] bf16.  HBM-floor bound (~13 us).
// ---------------------------------------------------------------------------
#define PAD_BLOCKS (NIMG * PD)                 // 1856
#define WT_BLOCKS  ((9 * C_OUT * C_IN) / 256)  // 1152

__global__ __launch_bounds__(256)
void prep_kernel(const float* __restrict__ x, const float* __restrict__ wgt,
                 __hip_bfloat16* __restrict__ xp, __hip_bfloat16* __restrict__ wt) {
    __shared__ float t[C_IN][HW + 1];
    const int b = blockIdx.x;
    if (b < PAD_BLOCKS) {
        const int hp = b % PD;
        const int n  = b / PD;
        const int h  = hp - 1;
        const bool interior = ((unsigned)h < (unsigned)HW);
        if (interior) {
            for (int idx = threadIdx.x; idx < C_IN * HW; idx += 256) {
                int ci = idx / HW, w = idx - ci * HW;
                t[ci][w] = x[((size_t)n * C_IN + ci) * SP + h * HW + w];
            }
        }
        __syncthreads();
        ushort4* dst = (ushort4*)(xp + ((size_t)n * PD + hp) * PD * C_IN);
        for (int idx = threadIdx.x; idx < PD * C_IN / 4; idx += 256) {
            int el = idx * 4;
            int wp = el >> 7, c0 = el & 127;
            ushort4 v = {0, 0, 0, 0};
            if (interior && wp >= 1 && wp <= HW) {
                int w = wp - 1;
                v.x = bf2u(t[c0 + 0][w]);
                v.y = bf2u(t[c0 + 1][w]);
                v.z = bf2u(t[c0 + 2][w]);
                v.w = bf2u(t[c0 + 3][w]);
            }
            dst[idx] = v;
        }
    } else {
        int idx = (b - PAD_BLOCKS) * 256 + threadIdx.x;   // 294912 exact
        int ci  = idx & 127;
        int co  = (idx >> 7) & 255;
        int tap = idx >> 15;
        wt[idx] = __float2bfloat16(wgt[(co * C_IN + ci) * 9 + tap]);
    }
}

// ---------------------------------------------------------------------------
// Main: implicit GEMM, 256x224 tile, 8 waves (4M x 2N, 64x112 each), A+B via
// LDS ring of 4 regions x 32 KB.  36 K-slices of 32.  Phase p:
//   VMCNT(4); BAR; RD(frags p+1 <- region (p+1)&3); STG(slice p+3); MM(p)
// Staging distance 3, in-flight 2 slices (8 loads); VMCNT(4) drains slice
// p+1 exactly (in-order vmem retirement).  Tail: phase 34 uses VMCNT(0)
// (slice 35 is the only outstanding stage - VMCNT(4) would not drain it).
// No lgkm pins: compiler inserts fine-grained lgkmcnt and interleaves the
// ds_reads into the MFMA stream.
// ---------------------------------------------------------------------------
__global__ __launch_bounds__(THREADS, 2)
void conv_mfma_kernel(const __hip_bfloat16* __restrict__ xp,
                      const __hip_bfloat16* __restrict__ wt,
                      const float* __restrict__ bias,
                      float* __restrict__ out) {
    extern __shared__ short smem[];   // 4 regions * 16384 shorts = 128 KiB

    const int tid  = threadIdx.x;
    const int lane = tid & 63;
    const int wid  = tid >> 6;
    const int rl   = lane & 15;
    const int kq   = lane >> 4;
    const int wg   = (blockIdx.x & 7) * 56 + (blockIdx.x >> 3);  // XCD-bijective
    const int s0   = wg * BN;

    // ---- staging constants (inverse-swizzled global source, rule #21) ----
    const int cg_el = (((lane & 3) ^ ((lane >> 3) & 3)) << 3);
    const int srow  = wid * 16 + (lane >> 2);        // 0..127
    const int aS0   = srow * C_IN + cg_el;           // A rows 0-127
    const int aS1   = aS0 + 128 * C_IN;              // A rows 128-255
    const int ldsw  = wid * 512;                     // wave-uniform LDS dest
    int s_r = s0 + srow;
    int n_  = s_r / SP, rem = s_r - n_ * SP;
    int h_  = rem / HW, w_ = rem - h_ * HW;
    const int bS0 = ((n_ * PD + h_) * PD + w_) * C_IN + cg_el;
    int srow2 = 128 + srow; if (srow2 > BN - 1) srow2 = BN - 1;   // dummy
    s_r = s0 + srow2;
    n_ = s_r / SP; rem = s_r - n_ * SP; h_ = rem / HW; w_ = rem - h_ * HW;
    const int bS1 = ((n_ * PD + h_) * PD + w_) * C_IN + cg_el;

    // ---- compute-phase read offsets (swizzled) ----
    const int rch = ((kq ^ ((lane >> 1) & 3)) << 3);
    const int wm  = (wid >> 1) * 64;    // 4 M-waves
    const int wn  = (wid & 1) * 112;    // 2 N-waves
    const int aRd = (wm + rl) * 32 + rch;
    const int bRd = (wn + rl) * 32 + rch;

    auto STG = [&](int s) {            // stage slice s into region s&3
        int tap = s >> 2, ci0 = (s & 3) << 5;
        const __hip_bfloat16* wsrc = wt + tap * (C_OUT * C_IN) + ci0;
        short* Ad = smem + (s & 3) * 16384 + ldsw;
        gload16(wsrc + aS0, Ad);
        gload16(wsrc + aS1, Ad + 4096);
        int kh = (tap * 11) >> 5, kw = tap - kh * 3;
        const __hip_bfloat16* xsrc = xp + (kh * PD + kw) * C_IN + ci0;
        short* Bd = smem + (s & 3) * 16384 + 8192 + ldsw;
        gload16(xsrc + bS0, Bd);
        gload16(xsrc + bS1, Bd + 4096);
    };
    auto RD = [&](bf16x8* fa, bf16x8* fb, int r) {
        const short* Ab = smem + r * 16384;
        const short* Bb = Ab + 8192;
        #pragma unroll
        for (int j = 0; j < 4; ++j) fa[j] = *(const bf16x8*)(Ab + aRd + j * 512);
        #pragma unroll
        for (int j = 0; j < 7; ++j) fb[j] = *(const bf16x8*)(Bb + bRd + j * 512);
    };

    // bias preload (tile-invariant)
    float bv[4][4];
    #pragma unroll
    for (int mi = 0; mi < 4; ++mi)
        #pragma unroll
        for (int j = 0; j < 4; ++j)
            bv[mi][j] = bias[wm + mi * 16 + (kq << 2) + j];

    f32x4 acc[4][7] = {};
    bf16x8 fa0[4], fb0[7], fa1[4], fb1[7];

    #define MM(FA, FB) do { \
        __builtin_amdgcn_s_setprio(1); \
        _Pragma("unroll") \
        for (int mi = 0; mi < 4; ++mi) \
            _Pragma("unroll") \
            for (int ni = 0; ni < 7; ++ni) \
                acc[mi][ni] = __builtin_amdgcn_mfma_f32_16x16x32_bf16( \
                    FA[mi], FB[ni], acc[mi][ni], 0, 0, 0); \
        __builtin_amdgcn_s_setprio(0); \
    } while (0)

    // ---- prologue: slices 0,1,2 staged; VMCNT(8) -> slice 0 landed ----
    STG(0); STG(1); STG(2);
    VMCNT(8);
    BAR();
    RD(fa0, fb0, 0);

    for (int t = 0; t < 18; ++t) {
        // ---- even phase p = 2t: MM slice 2t; read slice 2t+1 ----
        if (t == 17) { VMCNT(0); } else { VMCNT(4); }
        BAR();
        RD(fa1, fb1, (2 * t + 1) & 3);
        if (t <= 16) STG(2 * t + 3);
        MM(fa0, fb0);

        // ---- odd phase p = 2t+1: MM slice 2t+1; read slice 2t+2 ----
        if (t < 17) {
            VMCNT(4);
            BAR();
            RD(fa0, fb0, (2 * t + 2) & 3);
            if (t <= 15) STG(2 * t + 4);
            MM(fa1, fb1);
        } else {
            BAR();
            MM(fa1, fb1);
        }
    }
    #undef MM

    // ---- epilogue: D col = spatial (lane&15), row = co ----
    #pragma unroll
    for (int ni = 0; ni < 7; ++ni) {
        int s  = s0 + wn + ni * 16 + rl;
        int n  = s / SP;
        int si = s - n * SP;
        float* obase = out + (size_t)n * C_OUT * SP + si;
        #pragma unroll
        for (int mi = 0; mi < 4; ++mi) {
            int cob = wm + mi * 16 + (kq << 2);
            #pragma unroll
            for (int j = 0; j < 4; ++j) {
                obase[(size_t)(cob + j) * SP] = acc[mi][ni][j] + bv[mi][j];
            }
        }
    }
}

// ---------------------------------------------------------------------------
// Fallback: direct fp32 conv (only if ws too small). Slow but correct.
// ---------------------------------------------------------------------------
__global__ void conv_direct_kernel(const float* __restrict__ x,
                                   const float* __restrict__ wgt,
                                   const float* __restrict__ bias,
                                   float* __restrict__ out) {
    long idx = (long)blockIdx.x * 256 + threadIdx.x;
    if (idx >= (long)NIMG * C_OUT * SP) return;
    int si = (int)(idx % SP);
    int co = (int)((idx / SP) % C_OUT);
    int n  = (int)(idx / ((long)SP * C_OUT));
    int h = si / HW, w = si - (si / HW) * HW;
    float acc = bias[co];
    for (int ci = 0; ci < C_IN; ++ci) {
        const float* xr = x + ((size_t)n * C_IN + ci) * SP;
        const float* wr = wgt + ((size_t)co * C_IN + ci) * 9;
        #pragma unroll
        for (int kh = 0; kh < 3; ++kh) {
            int ih = h + kh - 1;
            if (ih < 0 || ih >= HW) continue;
            #pragma unroll
            for (int kw = 0; kw < 3; ++kw) {
                int iw = w + kw - 1;
                if (iw < 0 || iw >= HW) continue;
                acc += xr[ih * HW + iw] * wr[kh * 3 + kw];
            }
        }
    }
    out[idx] = acc;
}

// ---------------------------------------------------------------------------
extern "C" void kernel_launch(void* const* d_in, const int* in_sizes, int n_in,
                              void* d_out, int out_size, void* d_ws, size_t ws_size,
                              hipStream_t stream) {
    const float* x    = (const float*)d_in[0];
    const float* wgt  = (const float*)d_in[1];
    const float* bias = (const float*)d_in[2];
    float* out = (float*)d_out;

    const size_t xp_bytes = (size_t)NIMG * PD * PD * C_IN * sizeof(__hip_bfloat16);
    const size_t wt_bytes = (size_t)9 * C_OUT * C_IN * sizeof(__hip_bfloat16);

    if (ws_size >= xp_bytes + wt_bytes) {
        __hip_bfloat16* xp  = (__hip_bfloat16*)d_ws;
        __hip_bfloat16* wtb = (__hip_bfloat16*)((char*)d_ws + xp_bytes);

        prep_kernel<<<PAD_BLOCKS + WT_BLOCKS, 256, 0, stream>>>(x, wgt, xp, wtb);

        hipFuncSetAttribute((const void*)conv_mfma_kernel,
                            hipFuncAttributeMaxDynamicSharedMemorySize, 131072);
        conv_mfma_kernel<<<STOT / BN, THREADS, 131072, stream>>>(xp, wtb, bias, out);
    } else {
        long total = (long)NIMG * C_OUT * SP;
        conv_direct_kernel<<<(int)((total + 255) / 256), 256, 0, stream>>>(
            x, wgt, bias, out);
    }
}